// Round 1
// baseline (315.167 us; speedup 1.0000x reference)
//
#include <hip/hip_runtime.h>

#define NB 4096
#define TT 200
#define EE 64
#define H1 80
#define H2 40

__device__ __forceinline__ float sigmoid_fast(float x) {
    return 1.0f / (1.0f + __expf(-x));
}

__global__ __launch_bounds__(256) void din_attn_kernel(
    const float* __restrict__ queries,     // (B,1,E)
    const float* __restrict__ keys,        // (B,T,E)
    const int*   __restrict__ keys_length, // (B,1)
    const float* __restrict__ W1,          // (2E,H1)
    const float* __restrict__ b1,          // (H1)
    const float* __restrict__ W2,          // (H1,H2)
    const float* __restrict__ b2,          // (H2)
    const float* __restrict__ wk,          // (H2,1)
    const float* __restrict__ bias,        // (1)
    float* __restrict__ out)               // (B,1,E)
{
    const int b   = blockIdx.x;
    const int tid = threadIdx.x;

    __shared__ float qW1s[H1];
    __shared__ float sw[TT];
    __shared__ float sred[2];
    __shared__ float partial[4][EE];

    const float* q  = queries + (size_t)b * EE;
    const float* kb = keys + (size_t)b * TT * EE;

    // Phase A: q @ W1[:64] + b1  (once per batch; q reads are wave-uniform -> s_load)
    if (tid < H1) {
        float acc = b1[tid];
        #pragma unroll
        for (int i = 0; i < EE; ++i)
            acc = fmaf(q[i], W1[i * H1 + tid], acc);
        qW1s[tid] = acc;
    }
    const int len = keys_length[b];
    __syncthreads();

    const float NEG = -4294967296.0f;  // -(2^32)+1 rounded to f32

    // Phase B: per-key-position MLP; thread t owns key row t in registers.
    if (tid < TT) {
        float key[EE];
        const float* krow = kb + (size_t)tid * EE;
        #pragma unroll
        for (int i = 0; i < EE; i += 4) {
            float4 v = *reinterpret_cast<const float4*>(krow + i);
            key[i] = v.x; key[i+1] = v.y; key[i+2] = v.z; key[i+3] = v.w;
        }

        float h2acc[H2];
        #pragma unroll
        for (int k = 0; k < H2; ++k) h2acc[k] = b2[k];

        const float* W1k = W1 + EE * H1;  // rows 64..127 (key half)
        for (int jc = 0; jc < H1; jc += 8) {
            float acc[8];
            #pragma unroll
            for (int u = 0; u < 8; ++u) acc[u] = qW1s[jc + u];
            #pragma unroll
            for (int i = 0; i < EE; ++i) {
                // W1k index is wave-uniform -> scalar loads feeding FMAs
                #pragma unroll
                for (int u = 0; u < 8; ++u)
                    acc[u] = fmaf(key[i], W1k[i * H1 + jc + u], acc[u]);
            }
            #pragma unroll
            for (int u = 0; u < 8; ++u) {
                float h1 = sigmoid_fast(acc[u]);
                #pragma unroll
                for (int k = 0; k < H2; ++k)
                    h2acc[k] = fmaf(h1, W2[(jc + u) * H2 + k], h2acc[k]);
            }
        }

        float s = bias[0];
        #pragma unroll
        for (int k = 0; k < H2; ++k)
            s = fmaf(sigmoid_fast(h2acc[k]), wk[k], s);

        sw[tid] = (tid < len) ? s : NEG;
    }
    __syncthreads();

    // Softmax over T (masked). len==0 -> all equal NEG -> uniform weights (matches ref).
    if (tid < 64) {
        float m = sw[tid];
        for (int t = tid + 64; t < TT; t += 64) m = fmaxf(m, sw[t]);
        #pragma unroll
        for (int off = 32; off; off >>= 1) m = fmaxf(m, __shfl_down(m, off));
        if (tid == 0) sred[0] = m;
    }
    __syncthreads();
    const float m = sred[0];
    if (tid < TT) sw[tid] = __expf(sw[tid] - m);
    __syncthreads();
    if (tid < 64) {
        float sum = 0.f;
        for (int t = tid; t < TT; t += 64) sum += sw[t];
        #pragma unroll
        for (int off = 32; off; off >>= 1) sum += __shfl_down(sum, off);
        if (tid == 0) sred[1] = sum;
    }
    __syncthreads();
    const float inv = 1.0f / sred[1];

    // Weighted-sum pooling: wave w handles t = w, w+4, ...; lane i = feature (coalesced).
    const int w = tid >> 6, i = tid & 63;
    float acc = 0.f;
    for (int t = w; t < TT; t += 4)
        acc = fmaf(sw[t], kb[t * EE + i], acc);
    partial[w][i] = acc;
    __syncthreads();
    if (tid < EE)
        out[(size_t)b * EE + tid] =
            (partial[0][tid] + partial[1][tid] + partial[2][tid] + partial[3][tid]) * inv;
}

extern "C" void kernel_launch(void* const* d_in, const int* in_sizes, int n_in,
                              void* d_out, int out_size, void* d_ws, size_t ws_size,
                              hipStream_t stream) {
    const float* queries = (const float*)d_in[0];
    const float* keys    = (const float*)d_in[1];
    const int*   klen    = (const int*)d_in[2];
    const float* W1      = (const float*)d_in[3];
    const float* b1      = (const float*)d_in[4];
    const float* W2      = (const float*)d_in[5];
    const float* b2      = (const float*)d_in[6];
    const float* wk      = (const float*)d_in[7];
    const float* bias    = (const float*)d_in[8];
    float* out           = (float*)d_out;

    din_attn_kernel<<<NB, 256, 0, stream>>>(queries, keys, klen, W1, b1, W2, b2,
                                            wk, bias, out);
}

// Round 2
// 166.970 us; speedup vs baseline: 1.8876x; 1.8876x over previous
//
#include <hip/hip_runtime.h>

#define TT 200
#define EE 64

typedef unsigned short u16;
typedef unsigned int u32;
typedef __attribute__((ext_vector_type(8))) short bfrag;   // 8 bf16 in 4 VGPRs
typedef __attribute__((ext_vector_type(4))) float f32x4;

#define KLS_STRIDE 72    // u16 elems/row: 144 B (16B mult), bank stride 4 -> 2-way (free)
#define H1S_STRIDE 104   // u16 elems/row: 208 B (16B mult), bank stride 20 -> 2-way (free)

__device__ __forceinline__ u16 f2bf(float f) {
    u32 u = __float_as_uint(f);
    return (u16)((u + 0x7fffu + ((u >> 16) & 1u)) >> 16);  // RNE
}
__device__ __forceinline__ float bf2f(u16 h) {
    return __uint_as_float(((u32)h) << 16);
}
__device__ __forceinline__ float sigmoid_fast(float x) {
    return 1.0f / (1.0f + __expf(-x));
}

// Pre-pack W1k (rows 64..127 of W1) and W2 into MFMA B-fragment order.
// Slot bijection (MUST match A-frag loads in main kernel):
//   k = ks*32 + (lane>>4)*8 + j ,  n = nt*16 + (lane&15)
__global__ void prep_frags(const float* __restrict__ W1, const float* __restrict__ W2,
                           u16* __restrict__ B1f, u16* __restrict__ B2f) {
    int idx = blockIdx.x * 256 + threadIdx.x;
    if (idx < 5 * 2 * 64 * 8) {  // GEMM1: K=64 (2 ks), N=80 (5 nt)
        int j = idx & 7, l = (idx >> 3) & 63, ks = (idx >> 9) & 1, nt = idx >> 10;
        int k = ks * 32 + ((l >> 4) << 3) + j;
        int n = nt * 16 + (l & 15);
        B1f[idx] = f2bf(W1[(64 + k) * 80 + n]);
    }
    if (idx < 3 * 3 * 64 * 8) {  // GEMM2: K=96 pad (3 ks), N=48 pad (3 nt)
        int j = idx & 7, l = (idx >> 3) & 63, ks = (idx >> 9) % 3, nt = idx / 1536;
        int k = ks * 32 + ((l >> 4) << 3) + j;
        int n = nt * 16 + (l & 15);
        B2f[idx] = (k < 80 && n < 40) ? f2bf(W2[k * 40 + n]) : (u16)0;
    }
}

__global__ __launch_bounds__(256, 2) void din_mfma(
    const float* __restrict__ queries,     // (B,1,64)
    const float* __restrict__ keys,        // (B,200,64)
    const int*   __restrict__ keys_length, // (B,1)
    const float* __restrict__ W1,          // (128,80)
    const float* __restrict__ b1,          // (80)
    const float* __restrict__ b2,          // (40)
    const float* __restrict__ wk,          // (40)
    const float* __restrict__ bias,        // (1)
    const u16*   __restrict__ B1f,
    const u16*   __restrict__ B2f,
    float* __restrict__ out)               // (B,1,64)
{
    __shared__ __align__(16) u16 kls[208 * KLS_STRIDE];   // keys bf16 (rows 200..207 zero)
    __shared__ __align__(16) u16 h1s[208 * H1S_STRIDE];   // h1 bf16 (cols 80..95 zero)
    __shared__ float qb1s[80];
    __shared__ float sw[208];
    __shared__ float sred[2];
    __shared__ float partial[4][EE];

    const int b    = blockIdx.x;
    const int tid  = threadIdx.x;
    const int lane = tid & 63;
    const int wv   = tid >> 6;

    const float* kb = keys + (size_t)b * (TT * EE);
    const float* q  = queries + (size_t)b * EE;
    const int len   = keys_length[b];
    const float biass = bias[0];
    const float NEG = -4294967296.0f;

    // --- B1 fragments (global, L2-hot), per-lane wk / b2 ---
    bfrag b1fr[5][2];
    #pragma unroll
    for (int nt = 0; nt < 5; ++nt)
        #pragma unroll
        for (int ks = 0; ks < 2; ++ks)
            b1fr[nt][ks] = *reinterpret_cast<const bfrag*>(B1f + (((nt * 2 + ks) * 64 + lane) << 3));

    float wkf[3], b2init[3];
    #pragma unroll
    for (int nt = 0; nt < 3; ++nt) {
        int n = nt * 16 + (lane & 15);
        wkf[nt]    = (n < 40) ? wk[n] : 0.f;
        b2init[nt] = (n < 40) ? b2[n] : 0.f;
    }

    // --- stage keys -> LDS bf16 (coalesced float4 reads) ---
    for (int c = tid; c < (TT * EE) / 4; c += 256) {
        float4 v = reinterpret_cast<const float4*>(kb)[c];
        int row = (c * 4) / EE, col = (c * 4) % EE;
        ushort4 w4 = { f2bf(v.x), f2bf(v.y), f2bf(v.z), f2bf(v.w) };
        *reinterpret_cast<ushort4*>(&kls[row * KLS_STRIDE + col]) = w4;
    }
    // zero keys pad rows 200..207
    for (int z = tid; z < 8 * (KLS_STRIDE / 2); z += 256)
        reinterpret_cast<u32*>(kls)[200 * (KLS_STRIDE / 2) + z] = 0;
    // zero h1 pad cols 80..95 for all 208 rows
    for (int z = tid; z < 208 * 8; z += 256)
        reinterpret_cast<u32*>(h1s)[(z >> 3) * (H1S_STRIDE / 2) + 40 + (z & 7)] = 0;

    // --- qb1 = q @ W1[0:64] + b1 (wave-uniform q/W1 -> scalar loads) ---
    if (tid < 80) {
        float acc = b1[tid];
        #pragma unroll
        for (int i = 0; i < EE; ++i)
            acc = fmaf(q[i], W1[i * 80 + tid], acc);
        qb1s[tid] = acc;
    }
    __syncthreads();

    // --- GEMM1: h1 = sigmoid(keys @ W1k + qb1) ; acc init = qb1[col] ---
    float qinit[5];
    #pragma unroll
    for (int nt = 0; nt < 5; ++nt)
        qinit[nt] = qb1s[nt * 16 + (lane & 15)];

    for (int mt = wv; mt < 13; mt += 4) {
        const int arow = mt * 16 + (lane & 15);
        const u16* abase = &kls[arow * KLS_STRIDE + ((lane >> 4) << 3)];
        bfrag a0 = *reinterpret_cast<const bfrag*>(abase);
        bfrag a1 = *reinterpret_cast<const bfrag*>(abase + 32);
        const int hrow0 = mt * 16 + ((lane >> 4) << 2);
        #pragma unroll
        for (int nt = 0; nt < 5; ++nt) {
            f32x4 acc = { qinit[nt], qinit[nt], qinit[nt], qinit[nt] };
            acc = __builtin_amdgcn_mfma_f32_16x16x32_bf16(a0, b1fr[nt][0], acc, 0, 0, 0);
            acc = __builtin_amdgcn_mfma_f32_16x16x32_bf16(a1, b1fr[nt][1], acc, 0, 0, 0);
            const int hcol = nt * 16 + (lane & 15);
            #pragma unroll
            for (int r = 0; r < 4; ++r)
                h1s[(hrow0 + r) * H1S_STRIDE + hcol] = f2bf(sigmoid_fast(acc[r]));
        }
    }

    // --- B2 fragments ---
    bfrag b2fr[3][3];
    #pragma unroll
    for (int nt = 0; nt < 3; ++nt)
        #pragma unroll
        for (int ks = 0; ks < 3; ++ks)
            b2fr[nt][ks] = *reinterpret_cast<const bfrag*>(B2f + (((nt * 3 + ks) * 64 + lane) << 3));
    __syncthreads();

    // --- GEMM2 + score: sw[t] = (t<len) ? wk . sigmoid(h1@W2+b2) + bias : NEG ---
    for (int mt = wv; mt < 13; mt += 4) {
        const int arow = mt * 16 + (lane & 15);
        const u16* abase = &h1s[arow * H1S_STRIDE + ((lane >> 4) << 3)];
        bfrag a0 = *reinterpret_cast<const bfrag*>(abase);
        bfrag a1 = *reinterpret_cast<const bfrag*>(abase + 32);
        bfrag a2 = *reinterpret_cast<const bfrag*>(abase + 64);
        f32x4 cacc[3];
        #pragma unroll
        for (int nt = 0; nt < 3; ++nt) {
            f32x4 c = { b2init[nt], b2init[nt], b2init[nt], b2init[nt] };
            c = __builtin_amdgcn_mfma_f32_16x16x32_bf16(a0, b2fr[nt][0], c, 0, 0, 0);
            c = __builtin_amdgcn_mfma_f32_16x16x32_bf16(a1, b2fr[nt][1], c, 0, 0, 0);
            c = __builtin_amdgcn_mfma_f32_16x16x32_bf16(a2, b2fr[nt][2], c, 0, 0, 0);
            cacc[nt] = c;
        }
        const int row0 = mt * 16 + ((lane >> 4) << 2);
        #pragma unroll
        for (int r = 0; r < 4; ++r) {
            float p = sigmoid_fast(cacc[0][r]) * wkf[0]
                    + sigmoid_fast(cacc[1][r]) * wkf[1]
                    + sigmoid_fast(cacc[2][r]) * wkf[2];
            p += __shfl_xor(p, 1);
            p += __shfl_xor(p, 2);
            p += __shfl_xor(p, 4);
            p += __shfl_xor(p, 8);
            if ((lane & 15) == 0) {
                int row = row0 + r;
                sw[row] = (row < len) ? (p + biass) : NEG;
            }
        }
    }
    __syncthreads();

    // --- masked softmax over T=200 (len==0 -> uniform, matches ref) ---
    if (tid < 64) {
        float m = sw[tid];
        for (int t = tid + 64; t < TT; t += 64) m = fmaxf(m, sw[t]);
        #pragma unroll
        for (int off = 32; off; off >>= 1) m = fmaxf(m, __shfl_down(m, off));
        if (tid == 0) sred[0] = m;
    }
    __syncthreads();
    const float m = sred[0];
    if (tid < TT) sw[tid] = __expf(sw[tid] - m);
    __syncthreads();
    if (tid < 64) {
        float s = 0.f;
        for (int t = tid; t < TT; t += 64) s += sw[t];
        #pragma unroll
        for (int off = 32; off; off >>= 1) s += __shfl_down(s, off);
        if (tid == 0) sred[1] = s;
    }
    __syncthreads();
    const float inv = 1.0f / sred[1];

    // --- weighted-sum pooling from bf16 LDS keys (lane = feature, coalesced) ---
    float acc = 0.f;
    for (int t = wv; t < TT; t += 4)
        acc = fmaf(sw[t], bf2f(kls[t * KLS_STRIDE + lane]), acc);
    partial[wv][lane] = acc;
    __syncthreads();
    if (tid < EE)
        out[(size_t)b * EE + tid] =
            (partial[0][tid] + partial[1][tid] + partial[2][tid] + partial[3][tid]) * inv;
}

extern "C" void kernel_launch(void* const* d_in, const int* in_sizes, int n_in,
                              void* d_out, int out_size, void* d_ws, size_t ws_size,
                              hipStream_t stream) {
    const float* queries = (const float*)d_in[0];
    const float* keys    = (const float*)d_in[1];
    const int*   klen    = (const int*)d_in[2];
    const float* W1      = (const float*)d_in[3];
    const float* b1      = (const float*)d_in[4];
    const float* W2      = (const float*)d_in[5];
    const float* b2      = (const float*)d_in[6];
    const float* wk      = (const float*)d_in[7];
    const float* bias    = (const float*)d_in[8];
    float* out           = (float*)d_out;

    u16* B1f = (u16*)d_ws;
    u16* B2f = (u16*)((char*)d_ws + 10240);

    prep_frags<<<20, 256, 0, stream>>>(W1, W2, B1f, B2f);
    din_mfma<<<4096, 256, 0, stream>>>(queries, keys, klen, W1, b1, b2, wk, bias,
                                       B1f, B2f, out);
}